// Round 8
// baseline (108.994 us; speedup 1.0000x reference)
//
#include <hip/hip_runtime.h>

// Problem constants (from reference)
#define B_DIM 16384
#define IN_FEATURES 8192
#define OUT_FEATURES 1024
#define BLOCK_SIZE 8                     // IN_FEATURES / OUT_FEATURES
#define N_OUT (B_DIM * OUT_FEATURES)     // 16,777,216 outputs
#define N_F4 (B_DIM * IN_FEATURES / 4)   // 33,554,432 float4s of x

#define GRID 2048
#define BLOCK 256
#define NWAVES (GRID * BLOCK / 64)       // 8192 waves
#define F4_PER_WAVE_STEP 512             // 8 KiB per wave per step (8 loads)
#define STEP_F4 (NWAVES * F4_PER_WAVE_STEP)   // 4,194,304 f4/step (mult of 2048)
#define OUT_PER_STEP (STEP_F4 / 2)
#define N_STEPS (N_F4 / STEP_F4)         // 8, exact

// Native clang vector type — __builtin_nontemporal_load accepts these.
typedef float f32x4 __attribute__((ext_vector_type(4)));

// R6 structure (best: 106.6 us), ONE variable changed: stores are now regular
// write-back (NT removed) so L2 absorbs the 67 MB write stream and the memory
// controller can schedule writebacks during read lulls, instead of NT stores
// contending with the read stream in real time. Loads stay NT (512 MB,
// touched once — no reason to allocate).
__global__ __launch_bounds__(BLOCK) void blocklinear_nt8_wb_kernel(
        const float* __restrict__ x,
        const float* __restrict__ lw,
        float* __restrict__ y) {
    const int tid  = blockIdx.x * BLOCK + threadIdx.x;
    const int lane = threadIdx.x & 63;
    const int wave = tid >> 6;                 // global wave id [0, NWAVES)

    const f32x4* x4  = (const f32x4*)x;
    const f32x4* lw4 = (const f32x4*)lw;      // 2048 f4 = 32 KiB, cache-resident

    // Loop-invariant weight fragments (one-time exp), 8 float4s per lane.
    // Window: (wave*512 mod 2048) + 448 + 63 <= 2047 — no wrap.
    const int wi0 = (wave * F4_PER_WAVE_STEP + lane) & 2047;
    f32x4 w[8];
    #pragma unroll
    for (int j = 0; j < 8; ++j) {
        const f32x4 l = lw4[wi0 + j * 64];
        w[j].x = expf(l.x); w[j].y = expf(l.y);
        w[j].z = expf(l.z); w[j].w = expf(l.w);
    }

    size_t base = (size_t)wave * F4_PER_WAVE_STEP;  // f4 index of wave's chunk
    int    ob   = wave * (F4_PER_WAVE_STEP / 2);    // output index base
    const bool storer = ((lane & 1) == 0);
    const int  m = lane >> 1;                       // [0,32)

    #pragma unroll
    for (int s = 0; s < N_STEPS; ++s) {
        // Issue all eight wave-contiguous NT loads before consuming any.
        f32x4 xv[8];
        #pragma unroll
        for (int j = 0; j < 8; ++j)
            xv[j] = __builtin_nontemporal_load(&x4[base + j * 64 + lane]);

        float sv[8];
        #pragma unroll
        for (int j = 0; j < 8; ++j) {
            const float p = xv[j].x * w[j].x + xv[j].y * w[j].y
                          + xv[j].z * w[j].z + xv[j].w * w[j].w;
            sv[j] = p + __shfl_xor(p, 1, 64);     // pair-sum: full output
        }

        if (storer) {   // even lanes: eight 128B-contiguous WRITE-BACK stores
            #pragma unroll
            for (int j = 0; j < 8; ++j)
                y[ob + j * 32 + m] = sv[j];
        }
        base += STEP_F4;
        ob   += OUT_PER_STEP;
    }
}

extern "C" void kernel_launch(void* const* d_in, const int* in_sizes, int n_in,
                              void* d_out, int out_size, void* d_ws, size_t ws_size,
                              hipStream_t stream) {
    const float* x = (const float*)d_in[0];          // [B, IN_FEATURES] f32
    const float* log_weight = (const float*)d_in[1]; // [OUT_FEATURES, 8] f32
    float* y = (float*)d_out;                        // [B, OUT_FEATURES] f32

    blocklinear_nt8_wb_kernel<<<GRID, BLOCK, 0, stream>>>(x, log_weight, y);
}

// Round 9
// 107.016 us; speedup vs baseline: 1.0185x; 1.0185x over previous
//
#include <hip/hip_runtime.h>

// Problem constants (from reference)
#define B_DIM 16384
#define IN_FEATURES 8192
#define OUT_FEATURES 1024
#define BLOCK_SIZE 8                     // IN_FEATURES / OUT_FEATURES
#define N_OUT (B_DIM * OUT_FEATURES)     // 16,777,216 outputs
#define N_F4 (B_DIM * IN_FEATURES / 4)   // 33,554,432 float4s of x

#define GRID 2048
#define BLOCK 256
#define NWAVES (GRID * BLOCK / 64)       // 8192 waves (= 32 waves/CU, max occ)
#define F4_PER_WAVE_STEP 512             // 8 KiB per wave per step (8 loads)
#define STEP_F4 (NWAVES * F4_PER_WAVE_STEP)   // 4,194,304 f4/step (mult of 2048)
#define OUT_PER_STEP (STEP_F4 / 2)
#define N_STEPS (N_F4 / STEP_F4)         // 8, exact

// Native clang vector type — __builtin_nontemporal_load/store accept these.
typedef float f32x4 __attribute__((ext_vector_type(4)));

// Best variant (R6, 106.6 us = 5.67 TB/s effective, 90% of the 6.29 TB/s
// float4-copy ceiling). Wave-cooperative streaming, 8-deep NT load batching,
// NT stores. Tested and rejected: SW-pipeline reorder (R7, +1.5%), write-back
// stores (R8, +2.2%) — remaining gap to copy-BW is the read/write-mix floor.
__global__ __launch_bounds__(BLOCK) void blocklinear_nt8_kernel(
        const float* __restrict__ x,
        const float* __restrict__ lw,
        float* __restrict__ y) {
    const int tid  = blockIdx.x * BLOCK + threadIdx.x;
    const int lane = threadIdx.x & 63;
    const int wave = tid >> 6;                 // global wave id [0, NWAVES)

    const f32x4* x4  = (const f32x4*)x;
    const f32x4* lw4 = (const f32x4*)lw;      // 2048 f4 = 32 KiB, cache-resident

    // Loop-invariant weight fragments (one-time exp), 8 float4s per lane.
    // Window: (wave*512 mod 2048) + 448 + 63 <= 2047 — no wrap.
    const int wi0 = (wave * F4_PER_WAVE_STEP + lane) & 2047;
    f32x4 w[8];
    #pragma unroll
    for (int j = 0; j < 8; ++j) {
        const f32x4 l = lw4[wi0 + j * 64];
        w[j].x = expf(l.x); w[j].y = expf(l.y);
        w[j].z = expf(l.z); w[j].w = expf(l.w);
    }

    size_t base = (size_t)wave * F4_PER_WAVE_STEP;  // f4 index of wave's chunk
    int    ob   = wave * (F4_PER_WAVE_STEP / 2);    // output index base
    const bool storer = ((lane & 1) == 0);
    const int  m = lane >> 1;                       // [0,32)

    #pragma unroll
    for (int s = 0; s < N_STEPS; ++s) {
        // Issue all eight wave-contiguous NT loads before consuming any.
        f32x4 xv[8];
        #pragma unroll
        for (int j = 0; j < 8; ++j)
            xv[j] = __builtin_nontemporal_load(&x4[base + j * 64 + lane]);

        float sv[8];
        #pragma unroll
        for (int j = 0; j < 8; ++j) {
            const float p = xv[j].x * w[j].x + xv[j].y * w[j].y
                          + xv[j].z * w[j].z + xv[j].w * w[j].w;
            sv[j] = p + __shfl_xor(p, 1, 64);     // pair-sum: full output
        }

        if (storer) {   // even lanes: eight 128B-contiguous NT stores
            #pragma unroll
            for (int j = 0; j < 8; ++j)
                __builtin_nontemporal_store(sv[j], &y[ob + j * 32 + m]);
        }
        base += STEP_F4;
        ob   += OUT_PER_STEP;
    }
}

extern "C" void kernel_launch(void* const* d_in, const int* in_sizes, int n_in,
                              void* d_out, int out_size, void* d_ws, size_t ws_size,
                              hipStream_t stream) {
    const float* x = (const float*)d_in[0];          // [B, IN_FEATURES] f32
    const float* log_weight = (const float*)d_in[1]; // [OUT_FEATURES, 8] f32
    float* y = (float*)d_out;                        // [B, OUT_FEATURES] f32

    blocklinear_nt8_kernel<<<GRID, BLOCK, 0, stream>>>(x, log_weight, y);
}